// Round 1
// baseline (889.907 us; speedup 1.0000x reference)
//
#include <hip/hip_runtime.h>
#include <math.h>

#define NB 64
#define NN 1024
#define DQK 192
#define DV 64
#define KT 128

// ---------------------------------------------------------------------------
// prep: normalize vectors, compute q/k (c-major [B][192][N], q pre-scaled by
// 1/sqrt(192), k has metric folded) and v (token-major [B][N][64]).
// One block = 64 tokens, 256 threads.
// ---------------------------------------------------------------------------
__global__ __launch_bounds__(256) void prep_kernel(
    const float* __restrict__ vectors, const float* __restrict__ scalars,
    const float* __restrict__ Wq, const float* __restrict__ Wq_s, const float* __restrict__ bq_s,
    const float* __restrict__ Wk, const float* __restrict__ Wk_s, const float* __restrict__ bk_s,
    const float* __restrict__ Wv,
    float* __restrict__ qg, float* __restrict__ kg, float* __restrict__ vg)
{
    __shared__ float wq[512], wk[512], wv[256];
    __shared__ float wqs[4096], wks[4096];
    __shared__ float bq[64], bk[64];
    __shared__ float vl[64 * 65];   // normalized vectors, [tok][64] stride 65
    __shared__ float sl[64 * 65];   // scalars, later reused as v-out staging

    const int t = threadIdx.x;
    const int b = blockIdx.x >> 4;
    const int n0 = (blockIdx.x & 15) << 6;
    const long tok0 = (long)b * NN + n0;

    for (int i = t; i < 512; i += 256) { wq[i] = Wq[i]; wk[i] = Wk[i]; }
    if (t < 256) wv[t] = expf(Wv[t]);
    for (int i = t; i < 4096; i += 256) { wqs[i] = Wq_s[i]; wks[i] = Wk_s[i]; }
    if (t < 64) { bq[t] = bq_s[t]; bk[t] = bk_s[t]; }

    // stage vectors + scalars (coalesced float4 global reads)
    const float4* vin = (const float4*)(vectors + tok0 * 64);
    const float4* sin4 = (const float4*)(scalars + tok0 * 64);
#pragma unroll
    for (int r = 0; r < 4; ++r) {
        int i4 = t + (r << 8);                 // 0..1023
        int tok = i4 >> 4, c4 = (i4 & 15) << 2;
        float4 a = vin[i4];
        float* d = &vl[tok * 65 + c4];
        d[0] = a.x; d[1] = a.y; d[2] = a.z; d[3] = a.w;
        float4 s = sin4[i4];
        float* d2 = &sl[tok * 65 + c4];
        d2[0] = s.x; d2[1] = s.y; d2[2] = s.z; d2[3] = s.w;
    }
    __syncthreads();

    // Lorentz normalize in place: 1024 4-vectors, 4 per thread
#pragma unroll
    for (int r = 0; r < 4; ++r) {
        int g = t + (r << 8);
        float* p = &vl[(g >> 4) * 65 + ((g & 15) << 2)];
        float x0 = p[0], x1 = p[1], x2 = p[2], x3 = p[3];
        float nrm = x0 * x0 - x1 * x1 - x2 * x2 - x3 * x3;
        float inv = 1.0f / sqrtf(fmaxf(fabsf(nrm), 1e-5f));
        p[0] = x0 * inv; p[1] = x1 * inv; p[2] = x2 * inv; p[3] = x3 * inv;
    }
    __syncthreads();

    const int tx = t & 63;        // token within tile
    const int ty = t >> 6;        // 0..3 (wave id) -> wave-uniform feature
    const float SC = 0.07216878364870323f;  // 1/sqrt(192)

    // vector features f = 0..127
    for (int u = 0; u < 32; ++u) {
        int f = ty + (u << 2);
        int i = f >> 2, kc = f & 3;
        float aq = 0.f, ak = 0.f;
#pragma unroll
        for (int j = 0; j < 16; ++j) {
            float x = vl[tx * 65 + (j << 2) + kc];
            aq = fmaf(wq[i * 16 + j], x, aq);
            ak = fmaf(wk[i * 16 + j], x, ak);
        }
        long base = ((long)b * DQK + f) * NN + n0 + tx;
        qg[base] = aq * SC;
        kg[base] = (kc == 0) ? ak : -ak;       // metric fold
    }
    // scalar features f = 128..191
    for (int u = 0; u < 16; ++u) {
        int fs = ty + (u << 2);
        float aq = bq[fs], ak = bk[fs];
#pragma unroll 8
        for (int c = 0; c < 64; ++c) {
            float sv = sl[tx * 65 + c];
            aq = fmaf(wqs[(fs << 6) + c], sv, aq);
            ak = fmaf(wks[(fs << 6) + c], sv, ak);
        }
        long base = ((long)b * DQK + 128 + fs) * NN + n0 + tx;
        qg[base] = aq * SC;
        kg[base] = ak;
    }
    __syncthreads();   // all reads of sl done before reuse

    // v features into sl (reused as [tok][64] staging, stride 65)
    for (int u = 0; u < 16; ++u) {
        int f = ty + (u << 2);
        int i = f >> 2, kc = f & 3;
        float a = 0.f;
#pragma unroll
        for (int j = 0; j < 16; ++j)
            a = fmaf(wv[i * 16 + j], vl[tx * 65 + (j << 2) + kc], a);
        sl[tx * 65 + f] = a;
    }
    __syncthreads();
    // coalesced copy-out of v (token-major)
#pragma unroll
    for (int r = 0; r < 16; ++r) {
        int idx = t + (r << 8);                // 0..4095
        vg[tok0 * 64 + idx] = sl[(idx >> 6) * 65 + (idx & 63)];
    }
}

// ---------------------------------------------------------------------------
// flash attention, fp32 vector-ALU.
// Block: 256 threads (tx = t&15 -> keys/dv, ty = t>>4 -> queries).
// QT=64 queries/block, KT=128 keys/tile, c chunked by 32 for K staging.
// Thread score tile: 4q x 8k. Out tile: 4q x 4dv.
// ---------------------------------------------------------------------------
__global__ __launch_bounds__(256) void attn_kernel(
    const float* __restrict__ qg, const float* __restrict__ kg,
    const float* __restrict__ vg, float* __restrict__ out)
{
    __shared__ float Qt[DQK * 64];   // [c][64 queries]           48 KB
    __shared__ float Kc[32 * KT];    // [c-chunk 32][128 keys]    16 KB
    __shared__ float Vs[KT * 68];    // [key][64 dv] stride 68    34 KB
    __shared__ float Pt[KT * 68];    // [key][64 q ] stride 68    34 KB

    const int t = threadIdx.x;
    const int tx = t & 15, ty = t >> 4;
    const int b = blockIdx.y;
    const int n0 = blockIdx.x << 6;
    const float* qbase = qg + (long)b * DQK * NN;
    const float* kbase = kg + (long)b * DQK * NN;

    // stage full Q tile [192][64] (c-major rows are contiguous in global)
#pragma unroll
    for (int r = 0; r < 12; ++r) {
        int i4 = t + (r << 8);                 // 0..3071 float4
        int c = i4 >> 4, col = (i4 & 15) << 2;
        ((float4*)Qt)[i4] = *(const float4*)(qbase + (long)c * NN + n0 + col);
    }

    float m_run[4], l_run[4], acc[4][4];
#pragma unroll
    for (int i = 0; i < 4; ++i) {
        m_run[i] = -1e30f; l_run[i] = 0.f;
#pragma unroll
        for (int j = 0; j < 4; ++j) acc[i][j] = 0.f;
    }

    for (int kt = 0; kt < NN; kt += KT) {
        __syncthreads();                       // prev PV done before Vs overwrite
        // stage V tile [128][64] (token-major rows contiguous)
#pragma unroll
        for (int r = 0; r < 8; ++r) {
            int i4 = t + (r << 8);             // 0..2047 float4
            int kk = i4 >> 4, c = (i4 & 15) << 2;
            *(float4*)&Vs[kk * 68 + c] = *(const float4*)(vg + ((long)b * NN + kt + kk) * DV + c);
        }

        float s[4][8];
#pragma unroll
        for (int i = 0; i < 4; ++i)
#pragma unroll
            for (int j = 0; j < 8; ++j) s[i][j] = 0.f;

        for (int cc = 0; cc < DQK; cc += 32) {
            __syncthreads();                   // prev chunk compute done
#pragma unroll
            for (int r = 0; r < 4; ++r) {
                int i4 = t + (r << 8);         // 0..1023 float4
                int c = i4 >> 5, col = (i4 & 31) << 2;
                ((float4*)Kc)[i4] = *(const float4*)(kbase + (long)(cc + c) * NN + kt + col);
            }
            __syncthreads();
#pragma unroll
            for (int c = 0; c < 32; ++c) {
                float4 q4 = ((const float4*)Qt)[(cc + c) * 16 + ty];
                float4 ka = ((const float4*)Kc)[(c << 5) + tx];
                float4 kb = ((const float4*)Kc)[(c << 5) + 16 + tx];
                float qq[4] = {q4.x, q4.y, q4.z, q4.w};
                float va[4] = {ka.x, ka.y, ka.z, ka.w};
                float vb[4] = {kb.x, kb.y, kb.z, kb.w};
#pragma unroll
                for (int i = 0; i < 4; ++i)
#pragma unroll
                    for (int j = 0; j < 4; ++j) {
                        s[i][j]     = fmaf(qq[i], va[j], s[i][j]);
                        s[i][4 + j] = fmaf(qq[i], vb[j], s[i][4 + j]);
                    }
            }
        }

        // online softmax (row reductions across the 16 tx lanes)
#pragma unroll
        for (int i = 0; i < 4; ++i) {
            float m = s[i][0];
#pragma unroll
            for (int j = 1; j < 8; ++j) m = fmaxf(m, s[i][j]);
            m = fmaxf(m, __shfl_xor(m, 1));
            m = fmaxf(m, __shfl_xor(m, 2));
            m = fmaxf(m, __shfl_xor(m, 4));
            m = fmaxf(m, __shfl_xor(m, 8));
            float mn = fmaxf(m_run[i], m);
            float corr = __expf(m_run[i] - mn);
            m_run[i] = mn;
            float ps = 0.f;
#pragma unroll
            for (int j = 0; j < 8; ++j) { float e = __expf(s[i][j] - mn); s[i][j] = e; ps += e; }
            ps += __shfl_xor(ps, 1);
            ps += __shfl_xor(ps, 2);
            ps += __shfl_xor(ps, 4);
            ps += __shfl_xor(ps, 8);
            l_run[i] = l_run[i] * corr + ps;
#pragma unroll
            for (int j = 0; j < 4; ++j) acc[i][j] *= corr;
        }

        // write P transposed: Pt[key][query]
#pragma unroll
        for (int j = 0; j < 4; ++j) {
            *(float4*)&Pt[(tx * 4 + j) * 68 + ty * 4] =
                make_float4(s[0][j], s[1][j], s[2][j], s[3][j]);
            *(float4*)&Pt[(64 + tx * 4 + j) * 68 + ty * 4] =
                make_float4(s[0][4 + j], s[1][4 + j], s[2][4 + j], s[3][4 + j]);
        }
        __syncthreads();

        // PV: acc[q][dv] += P[q][k] * V[k][dv]
#pragma unroll 4
        for (int kk = 0; kk < KT; ++kk) {
            float4 p4 = *(const float4*)&Pt[kk * 68 + ty * 4];
            float4 v4 = *(const float4*)&Vs[kk * 68 + tx * 4];
            float pp[4] = {p4.x, p4.y, p4.z, p4.w};
            float vv[4] = {v4.x, v4.y, v4.z, v4.w};
#pragma unroll
            for (int i = 0; i < 4; ++i)
#pragma unroll
                for (int j = 0; j < 4; ++j)
                    acc[i][j] = fmaf(pp[i], vv[j], acc[i][j]);
        }
    }

    // epilogue: normalize and store [B,N,64] fp32
#pragma unroll
    for (int i = 0; i < 4; ++i) {
        float inv = 1.0f / l_run[i];
        float4 o = make_float4(acc[i][0] * inv, acc[i][1] * inv,
                               acc[i][2] * inv, acc[i][3] * inv);
        *(float4*)(out + ((long)b * NN + n0 + ty * 4 + i) * DV + tx * 4) = o;
    }
}

extern "C" void kernel_launch(void* const* d_in, const int* in_sizes, int n_in,
                              void* d_out, int out_size, void* d_ws, size_t ws_size,
                              hipStream_t stream) {
    const float* vectors = (const float*)d_in[0];
    const float* scalars = (const float*)d_in[1];
    const float* Wq   = (const float*)d_in[2];
    const float* Wq_s = (const float*)d_in[3];
    const float* bq_s = (const float*)d_in[4];
    const float* Wk   = (const float*)d_in[5];
    const float* Wk_s = (const float*)d_in[6];
    const float* bk_s = (const float*)d_in[7];
    const float* Wv   = (const float*)d_in[8];
    float* o = (float*)d_out;

    float* qg = (float*)d_ws;                              // [64][192][1024]
    float* kg = qg + (size_t)NB * DQK * NN;                // [64][192][1024]
    float* vg = kg + (size_t)NB * DQK * NN;                // [64][1024][64]

    prep_kernel<<<1024, 256, 0, stream>>>(vectors, scalars, Wq, Wq_s, bq_s,
                                          Wk, Wk_s, bk_s, Wv, qg, kg, vg);
    attn_kernel<<<dim3(16, NB), 256, 0, stream>>>(qg, kg, vg, o);
}

// Round 2
// 238.987 us; speedup vs baseline: 3.7237x; 3.7237x over previous
//
#include <hip/hip_runtime.h>
#include <math.h>

typedef float f32x16 __attribute__((ext_vector_type(16)));
typedef short bf16x8 __attribute__((ext_vector_type(8)));
typedef short bf16x4 __attribute__((ext_vector_type(4)));
typedef unsigned short u16;
typedef unsigned int u32;

#define MFMA32(a, b, c) __builtin_amdgcn_mfma_f32_32x32x16_bf16(a, b, c, 0, 0, 0)

__device__ __forceinline__ u16 f2bf(float x) {
    u32 u = __float_as_uint(x);
    u += 0x7FFFu + ((u >> 16) & 1u);
    return (u16)(u >> 16);
}
__device__ __forceinline__ float bf2f(u16 h) {
    return __uint_as_float(((u32)h) << 16);
}

// ---------------------------------------------------------------------------
// prep: normalize Lorentz vectors, build q/k embeddings (token-major [tok][192],
// q pre-scaled by 1/sqrt(192), k metric-folded) and V^T [b][dv][1024],
// all as bf16 hi/lo planes (hi = bf16(x), lo = bf16(x - hi)).
// ---------------------------------------------------------------------------
__global__ __launch_bounds__(256) void prep_kernel(
    const float* __restrict__ vectors, const float* __restrict__ scalars,
    const float* __restrict__ Wq, const float* __restrict__ Wq_s, const float* __restrict__ bq_s,
    const float* __restrict__ Wk, const float* __restrict__ Wk_s, const float* __restrict__ bk_s,
    const float* __restrict__ Wv,
    u16* __restrict__ qh, u16* __restrict__ ql,
    u16* __restrict__ kh, u16* __restrict__ kl,
    u16* __restrict__ vth, u16* __restrict__ vtl)
{
    __shared__ float wq[512], wk[512], wv[256];
    __shared__ float wqs[4096], wks[4096];
    __shared__ float bq[64], bk[64];
    __shared__ float vl[64 * 65];
    __shared__ float sl[64 * 65];
    __shared__ u32 ustq[64 * 65];
    __shared__ u32 ustk[64 * 65];

    const int t = threadIdx.x;
    const int b = blockIdx.x >> 4;
    const int n0 = (blockIdx.x & 15) << 6;
    const long tok0 = (long)b * 1024 + n0;

    for (int i = t; i < 512; i += 256) { wq[i] = Wq[i]; wk[i] = Wk[i]; }
    wv[t] = expf(Wv[t]);
    for (int i = t; i < 4096; i += 256) { wqs[i] = Wq_s[i]; wks[i] = Wk_s[i]; }
    if (t < 64) { bq[t] = bq_s[t]; bk[t] = bk_s[t]; }

    const float4* vin = (const float4*)(vectors + tok0 * 64);
    const float4* sin4 = (const float4*)(scalars + tok0 * 64);
#pragma unroll
    for (int r = 0; r < 4; ++r) {
        int i4 = t + (r << 8);
        int tok = i4 >> 4, c4 = (i4 & 15) << 2;
        float4 a = vin[i4];
        float* d = &vl[tok * 65 + c4];
        d[0] = a.x; d[1] = a.y; d[2] = a.z; d[3] = a.w;
        float4 s = sin4[i4];
        float* d2 = &sl[tok * 65 + c4];
        d2[0] = s.x; d2[1] = s.y; d2[2] = s.z; d2[3] = s.w;
    }
    __syncthreads();

#pragma unroll
    for (int r = 0; r < 4; ++r) {
        int gi = t + (r << 8);
        float* p = &vl[(gi >> 4) * 65 + ((gi & 15) << 2)];
        float x0 = p[0], x1 = p[1], x2 = p[2], x3 = p[3];
        float nrm = x0 * x0 - x1 * x1 - x2 * x2 - x3 * x3;
        float inv = 1.0f / sqrtf(fmaxf(fabsf(nrm), 1e-5f));
        p[0] = x0 * inv; p[1] = x1 * inv; p[2] = x2 * inv; p[3] = x3 * inv;
    }
    __syncthreads();

    const int tx = t & 63;
    const int ty = t >> 6;
    const float SC = 0.07216878364870323f;  // 1/sqrt(192)

    // ---- V -> ust [dv][tok] ----
    for (int u = 0; u < 16; ++u) {
        int f = ty + (u << 2);
        int i = f >> 2, kc = f & 3;
        float a = 0.f;
#pragma unroll
        for (int j = 0; j < 16; ++j)
            a = fmaf(wv[i * 16 + j], vl[tx * 65 + (j << 2) + kc], a);
        u16 hi = f2bf(a);
        u16 lo = f2bf(a - bf2f(hi));
        ustq[f * 65 + tx] = (u32)hi | ((u32)lo << 16);
    }
    __syncthreads();
#pragma unroll
    for (int r = 0; r < 16; ++r) {
        int i = t + (r << 8);
        int dv = i >> 6, tok = i & 63;
        u32 p = ustq[dv * 65 + tok];
        long o = ((long)b * 64 + dv) * 1024 + n0 + tok;
        vth[o] = (u16)(p & 0xFFFFu);
        vtl[o] = (u16)(p >> 16);
    }
    __syncthreads();

    // ---- Q/K in 3 feature-chunks of 64 ----
    for (int c0 = 0; c0 < 3; ++c0) {
        if (c0 < 2) {
            int f0 = c0 << 6;
            for (int u = 0; u < 16; ++u) {
                int fl = ty + (u << 2);
                int fv = f0 + fl;
                int i = fv >> 2, kc = fv & 3;
                float aq = 0.f, ak = 0.f;
#pragma unroll
                for (int j = 0; j < 16; ++j) {
                    float x = vl[tx * 65 + (j << 2) + kc];
                    aq = fmaf(wq[i * 16 + j], x, aq);
                    ak = fmaf(wk[i * 16 + j], x, ak);
                }
                aq *= SC;
                ak = (kc == 0) ? ak : -ak;     // metric fold
                u16 qhi = f2bf(aq); u16 qlo = f2bf(aq - bf2f(qhi));
                u16 khi = f2bf(ak); u16 klo = f2bf(ak - bf2f(khi));
                ustq[fl * 65 + tx] = (u32)qhi | ((u32)qlo << 16);
                ustk[fl * 65 + tx] = (u32)khi | ((u32)klo << 16);
            }
        } else {
            for (int u = 0; u < 16; ++u) {
                int fs = ty + (u << 2);
                float aq = bq[fs], ak = bk[fs];
#pragma unroll 8
                for (int c = 0; c < 64; ++c) {
                    float sv = sl[tx * 65 + c];
                    aq = fmaf(wqs[(fs << 6) + c], sv, aq);
                    ak = fmaf(wks[(fs << 6) + c], sv, ak);
                }
                aq *= SC;
                u16 qhi = f2bf(aq); u16 qlo = f2bf(aq - bf2f(qhi));
                u16 khi = f2bf(ak); u16 klo = f2bf(ak - bf2f(khi));
                ustq[fs * 65 + tx] = (u32)qhi | ((u32)qlo << 16);
                ustk[fs * 65 + tx] = (u32)khi | ((u32)klo << 16);
            }
        }
        __syncthreads();
        int f0 = c0 << 6;
#pragma unroll
        for (int r = 0; r < 16; ++r) {
            int i = t + (r << 8);
            int tok = i >> 6, fl = i & 63;
            u32 pq = ustq[fl * 65 + tok];
            u32 pk = ustk[fl * 65 + tok];
            long oq = (tok0 + tok) * 192 + f0 + fl;
            qh[oq] = (u16)(pq & 0xFFFFu); ql[oq] = (u16)(pq >> 16);
            kh[oq] = (u16)(pk & 0xFFFFu); kl[oq] = (u16)(pk >> 16);
        }
        __syncthreads();
    }
}

// ---------------------------------------------------------------------------
// MFMA flash attention. 4 waves x 32 q = 128 q/block; KT=32 keys/iter,
// double-buffered LDS; Q fragments resident in registers; swapped QK^T
// (S^T = K·Q) so softmax is per-lane + one shfl_xor(32), and P feeds the
// PV MFMA's B operand in-register.
// ---------------------------------------------------------------------------
__global__ __launch_bounds__(256, 2) void attn_kernel(
    const u16* __restrict__ qh, const u16* __restrict__ ql,
    const u16* __restrict__ kh, const u16* __restrict__ kl,
    const u16* __restrict__ vth, const u16* __restrict__ vtl,
    float* __restrict__ out)
{
    __shared__ u16 KH[2 * 32 * 200];   // [buf][key32][c 192+pad8]
    __shared__ u16 KL[2 * 32 * 200];
    __shared__ u16 VH[2 * 64 * 40];    // [buf][dv64][key 32+pad8]
    __shared__ u16 VL[2 * 64 * 40];

    const int t = threadIdx.x;
    const int lane = t & 63;
    const int w = t >> 6;
    const int l31 = lane & 31, g = lane >> 5;

    const int bid = blockIdx.x;
    const int b = ((bid & 7) << 3) + ((bid >> 3) >> 3);   // XCD-batch swizzle
    const int qt = (bid >> 3) & 7;

    // ---- Q fragments (registers, held all iterations) ----
    const long qtok = (long)b * 1024 + qt * 128 + w * 32 + l31;
    const u16* qhp = qh + qtok * 192 + g * 8;
    const u16* qlp = ql + qtok * 192 + g * 8;
    bf16x8 Qh[12], Ql[12];
#pragma unroll
    for (int c = 0; c < 12; ++c) {
        Qh[c] = *(const bf16x8*)(qhp + c * 16);
        Ql[c] = *(const bf16x8*)(qlp + c * 16);
    }

    // ---- staging pointers ----
    const int skk = t >> 3, scs = t & 7;          // K: row skk, 24 u16 from scs*24
    const u16* kh_g = kh + ((long)b * 1024 + skk) * 192 + scs * 24;
    const u16* kl_g = kl + ((long)b * 1024 + skk) * 192 + scs * 24;
    const int sdv = t >> 2, ssg = t & 3;          // V^T: row sdv, 8 keys from ssg*8
    const u16* vh_g = vth + ((long)b * 64 + sdv) * 1024 + ssg * 8;
    const u16* vl_g = vtl + ((long)b * 64 + sdv) * 1024 + ssg * 8;
    u16* kh_d = KH + skk * 200 + scs * 24;
    u16* kl_d = KL + skk * 200 + scs * 24;
    u16* vh_d = VH + sdv * 40 + ssg * 8;
    u16* vl_d = VL + sdv * 40 + ssg * 8;

    int4 ra0, ra1, ra2, rb0, rb1, rb2, rc0, rd0;

#define LOADT(kt) do { \
        const u16* p1 = kh_g + (long)(kt) * 192; \
        ra0 = *(const int4*)(p1); ra1 = *(const int4*)(p1 + 8); ra2 = *(const int4*)(p1 + 16); \
        const u16* p2 = kl_g + (long)(kt) * 192; \
        rb0 = *(const int4*)(p2); rb1 = *(const int4*)(p2 + 8); rb2 = *(const int4*)(p2 + 16); \
        rc0 = *(const int4*)(vh_g + (kt)); \
        rd0 = *(const int4*)(vl_g + (kt)); \
    } while (0)

#define WRITET(buf) do { \
        u16* d1 = kh_d + (buf) * 6400; \
        *(int4*)(d1) = ra0; *(int4*)(d1 + 8) = ra1; *(int4*)(d1 + 16) = ra2; \
        u16* d2 = kl_d + (buf) * 6400; \
        *(int4*)(d2) = rb0; *(int4*)(d2 + 8) = rb1; *(int4*)(d2 + 16) = rb2; \
        *(int4*)(vh_d + (buf) * 2560) = rc0; \
        *(int4*)(vl_d + (buf) * 2560) = rd0; \
    } while (0)

    f32x16 o0, o1;
#pragma unroll
    for (int r = 0; r < 16; ++r) { o0[r] = 0.f; o1[r] = 0.f; }
    float m_run = -1e30f, l_run = 0.f;

    LOADT(0);
    WRITET(0);
    __syncthreads();

    for (int it = 0; it < 32; ++it) {
        const int cb = it & 1;
        if (it < 31) LOADT((it + 1) * 32);

        // ---- QK^T (swapped): S^T[key][q], 3 hi/lo passes, 2 indep chains ----
        f32x16 sA, sB;
#pragma unroll
        for (int r = 0; r < 16; ++r) { sA[r] = 0.f; sB[r] = 0.f; }
        const u16* krh = KH + cb * 6400 + l31 * 200 + g * 8;
        const u16* krl = KL + cb * 6400 + l31 * 200 + g * 8;
#pragma unroll
        for (int c = 0; c < 12; ++c) {
            bf16x8 fh = *(const bf16x8*)(krh + c * 16);
            bf16x8 fl = *(const bf16x8*)(krl + c * 16);
            sA = MFMA32(fh, Qh[c], sA);
            sB = MFMA32(fh, Ql[c], sB);
            sB = MFMA32(fl, Qh[c], sB);
        }

        // ---- online softmax (per-lane 16 keys + one cross-half shuffle) ----
        float s[16];
#pragma unroll
        for (int r = 0; r < 16; ++r) s[r] = sA[r] + sB[r];
        float mt = s[0];
#pragma unroll
        for (int r = 1; r < 16; ++r) mt = fmaxf(mt, s[r]);
        mt = fmaxf(mt, __shfl_xor(mt, 32));
        float mn = fmaxf(m_run, mt);
        float corr = __expf(m_run - mn);
        m_run = mn;
        float ps = 0.f;
#pragma unroll
        for (int r = 0; r < 16; ++r) { s[r] = __expf(s[r] - mn); ps += s[r]; }
        ps += __shfl_xor(ps, 32);
        l_run = l_run * corr + ps;
#pragma unroll
        for (int r = 0; r < 16; ++r) { o0[r] *= corr; o1[r] *= corr; }

        // ---- P -> bf16 hi/lo, packed per 16-key chunk (in-register B op) ----
        bf16x8 ph0, ph1, pl0, pl1;
#pragma unroll
        for (int e = 0; e < 8; ++e) {
            float x0 = s[e];
            u16 h0 = f2bf(x0);
            ph0[e] = (short)h0; pl0[e] = (short)f2bf(x0 - bf2f(h0));
            float x1 = s[8 + e];
            u16 h1 = f2bf(x1);
            ph1[e] = (short)h1; pl1[e] = (short)f2bf(x1 - bf2f(h1));
        }

        // ---- PV: out^T[dv][q] += V^T · P^T, 3 hi/lo passes ----
        const u16* vbh = VH + cb * 2560;
        const u16* vbl = VL + cb * 2560;
#pragma unroll
        for (int d = 0; d < 2; ++d) {
            f32x16 acc = d ? o1 : o0;
#pragma unroll
            for (int c = 0; c < 2; ++c) {
                const u16* ph_ = vbh + (d * 32 + l31) * 40 + c * 16 + g * 4;
                const u16* pl_ = vbl + (d * 32 + l31) * 40 + c * 16 + g * 4;
                bf16x4 h0 = *(const bf16x4*)(ph_);
                bf16x4 h1 = *(const bf16x4*)(ph_ + 8);
                bf16x4 l0 = *(const bf16x4*)(pl_);
                bf16x4 l1 = *(const bf16x4*)(pl_ + 8);
                bf16x8 vh8 = __builtin_shufflevector(h0, h1, 0, 1, 2, 3, 4, 5, 6, 7);
                bf16x8 vl8 = __builtin_shufflevector(l0, l1, 0, 1, 2, 3, 4, 5, 6, 7);
                bf16x8 pc = c ? ph1 : ph0;
                bf16x8 plc = c ? pl1 : pl0;
                acc = MFMA32(vh8, pc, acc);
                acc = MFMA32(vl8, pc, acc);
                acc = MFMA32(vh8, plc, acc);
            }
            if (d) o1 = acc; else o0 = acc;
        }

        if (it < 31) WRITET(cb ^ 1);
        __syncthreads();
    }

    // ---- epilogue ----
    float inv = 1.0f / l_run;
    float* op = out + qtok * 64;
#pragma unroll
    for (int d = 0; d < 2; ++d) {
#pragma unroll
        for (int sg = 0; sg < 4; ++sg) {
            float4 o4;
            if (d == 0) o4 = make_float4(o0[4*sg+0]*inv, o0[4*sg+1]*inv, o0[4*sg+2]*inv, o0[4*sg+3]*inv);
            else        o4 = make_float4(o1[4*sg+0]*inv, o1[4*sg+1]*inv, o1[4*sg+2]*inv, o1[4*sg+3]*inv);
            *(float4*)(op + d * 32 + sg * 8 + g * 4) = o4;
        }
    }
#undef LOADT
#undef WRITET
}

extern "C" void kernel_launch(void* const* d_in, const int* in_sizes, int n_in,
                              void* d_out, int out_size, void* d_ws, size_t ws_size,
                              hipStream_t stream) {
    const float* vectors = (const float*)d_in[0];
    const float* scalars = (const float*)d_in[1];
    const float* Wq   = (const float*)d_in[2];
    const float* Wq_s = (const float*)d_in[3];
    const float* bq_s = (const float*)d_in[4];
    const float* Wk   = (const float*)d_in[5];
    const float* Wk_s = (const float*)d_in[6];
    const float* bk_s = (const float*)d_in[7];
    const float* Wv   = (const float*)d_in[8];
    float* o = (float*)d_out;

    u16* qh  = (u16*)d_ws;                 // 64*1024*192
    u16* ql  = qh + 12582912;
    u16* kh  = ql + 12582912;
    u16* kl  = kh + 12582912;
    u16* vth = kl + 12582912;              // 64*64*1024
    u16* vtl = vth + 4194304;

    prep_kernel<<<1024, 256, 0, stream>>>(vectors, scalars, Wq, Wq_s, bq_s,
                                          Wk, Wk_s, bk_s, Wv,
                                          qh, ql, kh, kl, vth, vtl);
    attn_kernel<<<512, 256, 0, stream>>>(qh, ql, kh, kl, vth, vtl, o);
}

// Round 3
// 177.690 us; speedup vs baseline: 5.0082x; 1.3450x over previous
//
#include <hip/hip_runtime.h>
#include <math.h>

typedef float f32x16 __attribute__((ext_vector_type(16)));
typedef short bf16x8 __attribute__((ext_vector_type(8)));
typedef short bf16x4 __attribute__((ext_vector_type(4)));
typedef unsigned short u16;
typedef unsigned int u32;

#define MFMA32(a, b, c) __builtin_amdgcn_mfma_f32_32x32x16_bf16(a, b, c, 0, 0, 0)

__device__ __forceinline__ u16 f2bf(float x) {
    u32 u = __float_as_uint(x);
    u += 0x7FFFu + ((u >> 16) & 1u);
    return (u16)(u >> 16);
}
__device__ __forceinline__ float bf2f(u16 h) {
    return __uint_as_float(((u32)h) << 16);
}

// ---------------------------------------------------------------------------
// prep: lane-per-feature mapping, weights in registers.
//   wave0: q vector features f=2*lane, 2*lane+1 (u32-packed coalesced stores)
//   wave1: k vector features (metric folded) + V features (via LDS transpose)
//   wave2: q scalar features (64-reg weight row, broadcast b128 LDS reads)
//   wave3: k scalar features
// Outputs: qh/ql/kh/kl token-major [tok][192] bf16 planes, vth/vtl [b][dv][1024].
// ---------------------------------------------------------------------------
__global__ __launch_bounds__(256) void prep_kernel(
    const float* __restrict__ vectors, const float* __restrict__ scalars,
    const float* __restrict__ Wq, const float* __restrict__ Wq_s, const float* __restrict__ bq_s,
    const float* __restrict__ Wk, const float* __restrict__ Wk_s, const float* __restrict__ bk_s,
    const float* __restrict__ Wv,
    u16* __restrict__ qh, u16* __restrict__ ql,
    u16* __restrict__ kh, u16* __restrict__ kl,
    u16* __restrict__ vth, u16* __restrict__ vtl)
{
    __shared__ float vl[64 * 68];    // normalized vectors [tok][64]
    __shared__ float sl[64 * 68];    // scalars [tok][64]
    __shared__ u32 vst[64 * 65];     // v staging [dv][tok], hi | lo<<16

    const int t = threadIdx.x;
    const int lane = t & 63;
    const int w = t >> 6;
    const int b = blockIdx.x >> 4;
    const int n0 = (blockIdx.x & 15) << 6;
    const long tok0 = (long)b * 1024 + n0;

    // ---- stage inputs (coalesced float4) ----
    const float4* vin = (const float4*)(vectors + tok0 * 64);
    const float4* sin4 = (const float4*)(scalars + tok0 * 64);
#pragma unroll
    for (int r = 0; r < 4; ++r) {
        int i4 = t + (r << 8);
        int tok = i4 >> 4, c4 = (i4 & 15) << 2;
        *(float4*)&vl[tok * 68 + c4] = vin[i4];
        *(float4*)&sl[tok * 68 + c4] = sin4[i4];
    }

    // ---- weight registers (role-dependent, loads overlap staging) ----
    float wr0[16], wr1[16];
    float wsr[64];
    float bias = 0.f;
    if (w == 0) {
        int row = lane >> 1;
#pragma unroll
        for (int j = 0; j < 16; ++j) wr0[j] = Wq[row * 16 + j];
    } else if (w == 1) {
        int row = lane >> 1;
        int vrow = lane >> 2;
#pragma unroll
        for (int j = 0; j < 16; ++j) {
            wr0[j] = Wk[row * 16 + j];
            wr1[j] = expf(Wv[vrow * 16 + j]);
        }
    } else if (w == 2) {
#pragma unroll
        for (int c4 = 0; c4 < 16; ++c4) {
            float4 x = *(const float4*)(Wq_s + lane * 64 + c4 * 4);
            wsr[c4 * 4 + 0] = x.x; wsr[c4 * 4 + 1] = x.y;
            wsr[c4 * 4 + 2] = x.z; wsr[c4 * 4 + 3] = x.w;
        }
        bias = bq_s[lane];
    } else {
#pragma unroll
        for (int c4 = 0; c4 < 16; ++c4) {
            float4 x = *(const float4*)(Wk_s + lane * 64 + c4 * 4);
            wsr[c4 * 4 + 0] = x.x; wsr[c4 * 4 + 1] = x.y;
            wsr[c4 * 4 + 2] = x.z; wsr[c4 * 4 + 3] = x.w;
        }
        bias = bk_s[lane];
    }
    __syncthreads();

    // ---- Lorentz normalize in place ----
#pragma unroll
    for (int r = 0; r < 4; ++r) {
        int gi = t + (r << 8);
        float* p = &vl[(gi >> 4) * 68 + ((gi & 15) << 2)];
        float x0 = p[0], x1 = p[1], x2 = p[2], x3 = p[3];
        float nrm = x0 * x0 - x1 * x1 - x2 * x2 - x3 * x3;
        float inv = 1.0f / sqrtf(fmaxf(fabsf(nrm), 1e-5f));
        p[0] = x0 * inv; p[1] = x1 * inv; p[2] = x2 * inv; p[3] = x3 * inv;
    }
    __syncthreads();

    const float SC = 0.07216878364870323f;   // 1/sqrt(192)

    if (w == 0) {
        // q vector features f = 2*lane, 2*lane+1
        const int c0 = (lane & 1) << 1;
        u32* qh32 = (u32*)qh;
        u32* ql32 = (u32*)ql;
        for (int tok = 0; tok < 64; ++tok) {
            float a0 = 0.f, a1 = 0.f;
            const float* vp = &vl[tok * 68 + c0];
#pragma unroll
            for (int j = 0; j < 16; ++j) {
                float2 x = *(const float2*)(vp + j * 4);
                a0 = fmaf(wr0[j], x.x, a0);
                a1 = fmaf(wr0[j], x.y, a1);
            }
            a0 *= SC; a1 *= SC;
            u16 h0 = f2bf(a0), h1 = f2bf(a1);
            u16 lo0 = f2bf(a0 - bf2f(h0)), lo1 = f2bf(a1 - bf2f(h1));
            long rowo = (tok0 + tok) * 96 + lane;
            qh32[rowo] = (u32)h0 | ((u32)h1 << 16);
            ql32[rowo] = (u32)lo0 | ((u32)lo1 << 16);
        }
    } else if (w == 1) {
        // k vector features (metric fold) + v feature = lane
        const int c0 = (lane & 1) << 1;
        const int vc = lane & 3;
        const float sg0 = (c0 == 0) ? 1.f : -1.f;
        u32* kh32 = (u32*)kh;
        u32* kl32 = (u32*)kl;
        for (int tok = 0; tok < 64; ++tok) {
            float a0 = 0.f, a1 = 0.f, av = 0.f;
            const float* vp = &vl[tok * 68];
#pragma unroll
            for (int j = 0; j < 16; ++j) {
                float2 x = *(const float2*)(vp + j * 4 + c0);
                a0 = fmaf(wr0[j], x.x, a0);
                a1 = fmaf(wr0[j], x.y, a1);
                av = fmaf(wr1[j], vp[j * 4 + vc], av);
            }
            a0 *= sg0; a1 = -a1;   // comps c0 (+ iff 0), c0+1 (always -)
            u16 h0 = f2bf(a0), h1 = f2bf(a1), hv = f2bf(av);
            u16 lo0 = f2bf(a0 - bf2f(h0)), lo1 = f2bf(a1 - bf2f(h1));
            u16 lv = f2bf(av - bf2f(hv));
            long rowo = (tok0 + tok) * 96 + lane;
            kh32[rowo] = (u32)h0 | ((u32)h1 << 16);
            kl32[rowo] = (u32)lo0 | ((u32)lo1 << 16);
            vst[lane * 65 + tok] = (u32)hv | ((u32)lv << 16);
        }
    } else {
        // scalar features 128+lane (wave2: q, wave3: k)
        const int isq = (w == 2);
        u16* oh = isq ? qh : kh;
        u16* ol = isq ? ql : kl;
        const float sc = isq ? SC : 1.f;
        for (int tok = 0; tok < 64; ++tok) {
            float a = bias;
            const float* sp = &sl[tok * 68];
#pragma unroll
            for (int c4 = 0; c4 < 16; ++c4) {
                float4 x = *(const float4*)(sp + c4 * 4);
                a = fmaf(wsr[c4 * 4 + 0], x.x, a);
                a = fmaf(wsr[c4 * 4 + 1], x.y, a);
                a = fmaf(wsr[c4 * 4 + 2], x.z, a);
                a = fmaf(wsr[c4 * 4 + 3], x.w, a);
            }
            a *= sc;
            u16 h = f2bf(a), lo2 = f2bf(a - bf2f(h));
            long o = (tok0 + tok) * 192 + 128 + lane;
            oh[o] = h; ol[o] = lo2;
        }
    }
    __syncthreads();

    // ---- coalesced v copy-out ----
#pragma unroll
    for (int r = 0; r < 16; ++r) {
        int i = t + (r << 8);
        int dv = i >> 6, tok = i & 63;
        u32 p = vst[dv * 65 + tok];
        long o = ((long)b * 64 + dv) * 1024 + n0 + tok;
        vth[o] = (u16)(p & 0xFFFFu);
        vtl[o] = (u16)(p >> 16);
    }
}

// ---------------------------------------------------------------------------
// MFMA flash attention (unchanged structure + T5 setprio around MFMA clusters).
// ---------------------------------------------------------------------------
__global__ __launch_bounds__(256, 2) void attn_kernel(
    const u16* __restrict__ qh, const u16* __restrict__ ql,
    const u16* __restrict__ kh, const u16* __restrict__ kl,
    const u16* __restrict__ vth, const u16* __restrict__ vtl,
    float* __restrict__ out)
{
    __shared__ u16 KH[2 * 32 * 200];
    __shared__ u16 KL[2 * 32 * 200];
    __shared__ u16 VH[2 * 64 * 40];
    __shared__ u16 VL[2 * 64 * 40];

    const int t = threadIdx.x;
    const int lane = t & 63;
    const int w = t >> 6;
    const int l31 = lane & 31, g = lane >> 5;

    const int bid = blockIdx.x;
    const int b = ((bid & 7) << 3) + ((bid >> 3) >> 3);
    const int qt = (bid >> 3) & 7;

    const long qtok = (long)b * 1024 + qt * 128 + w * 32 + l31;
    const u16* qhp = qh + qtok * 192 + g * 8;
    const u16* qlp = ql + qtok * 192 + g * 8;
    bf16x8 Qh[12], Ql[12];
#pragma unroll
    for (int c = 0; c < 12; ++c) {
        Qh[c] = *(const bf16x8*)(qhp + c * 16);
        Ql[c] = *(const bf16x8*)(qlp + c * 16);
    }

    const int skk = t >> 3, scs = t & 7;
    const u16* kh_g = kh + ((long)b * 1024 + skk) * 192 + scs * 24;
    const u16* kl_g = kl + ((long)b * 1024 + skk) * 192 + scs * 24;
    const int sdv = t >> 2, ssg = t & 3;
    const u16* vh_g = vth + ((long)b * 64 + sdv) * 1024 + ssg * 8;
    const u16* vl_g = vtl + ((long)b * 64 + sdv) * 1024 + ssg * 8;
    u16* kh_d = KH + skk * 200 + scs * 24;
    u16* kl_d = KL + skk * 200 + scs * 24;
    u16* vh_d = VH + sdv * 40 + ssg * 8;
    u16* vl_d = VL + sdv * 40 + ssg * 8;

    int4 ra0, ra1, ra2, rb0, rb1, rb2, rc0, rd0;

#define LOADT(kt) do { \
        const u16* p1 = kh_g + (long)(kt) * 192; \
        ra0 = *(const int4*)(p1); ra1 = *(const int4*)(p1 + 8); ra2 = *(const int4*)(p1 + 16); \
        const u16* p2 = kl_g + (long)(kt) * 192; \
        rb0 = *(const int4*)(p2); rb1 = *(const int4*)(p2 + 8); rb2 = *(const int4*)(p2 + 16); \
        rc0 = *(const int4*)(vh_g + (kt)); \
        rd0 = *(const int4*)(vl_g + (kt)); \
    } while (0)

#define WRITET(buf) do { \
        u16* d1 = kh_d + (buf) * 6400; \
        *(int4*)(d1) = ra0; *(int4*)(d1 + 8) = ra1; *(int4*)(d1 + 16) = ra2; \
        u16* d2 = kl_d + (buf) * 6400; \
        *(int4*)(d2) = rb0; *(int4*)(d2 + 8) = rb1; *(int4*)(d2 + 16) = rb2; \
        *(int4*)(vh_d + (buf) * 2560) = rc0; \
        *(int4*)(vl_d + (buf) * 2560) = rd0; \
    } while (0)

    f32x16 o0, o1;
#pragma unroll
    for (int r = 0; r < 16; ++r) { o0[r] = 0.f; o1[r] = 0.f; }
    float m_run = -1e30f, l_run = 0.f;

    LOADT(0);
    WRITET(0);
    __syncthreads();

    for (int it = 0; it < 32; ++it) {
        const int cb = it & 1;
        if (it < 31) LOADT((it + 1) * 32);

        f32x16 sA, sB;
#pragma unroll
        for (int r = 0; r < 16; ++r) { sA[r] = 0.f; sB[r] = 0.f; }
        const u16* krh = KH + cb * 6400 + l31 * 200 + g * 8;
        const u16* krl = KL + cb * 6400 + l31 * 200 + g * 8;
        __builtin_amdgcn_s_setprio(1);
#pragma unroll
        for (int c = 0; c < 12; ++c) {
            bf16x8 fh = *(const bf16x8*)(krh + c * 16);
            bf16x8 fl = *(const bf16x8*)(krl + c * 16);
            sA = MFMA32(fh, Qh[c], sA);
            sB = MFMA32(fh, Ql[c], sB);
            sB = MFMA32(fl, Qh[c], sB);
        }
        __builtin_amdgcn_s_setprio(0);

        float s[16];
#pragma unroll
        for (int r = 0; r < 16; ++r) s[r] = sA[r] + sB[r];
        float mt = s[0];
#pragma unroll
        for (int r = 1; r < 16; ++r) mt = fmaxf(mt, s[r]);
        mt = fmaxf(mt, __shfl_xor(mt, 32));
        float mn = fmaxf(m_run, mt);
        float corr = __expf(m_run - mn);
        m_run = mn;
        float ps = 0.f;
#pragma unroll
        for (int r = 0; r < 16; ++r) { s[r] = __expf(s[r] - mn); ps += s[r]; }
        ps += __shfl_xor(ps, 32);
        l_run = l_run * corr + ps;
#pragma unroll
        for (int r = 0; r < 16; ++r) { o0[r] *= corr; o1[r] *= corr; }

        bf16x8 ph0, ph1, pl0, pl1;
#pragma unroll
        for (int e = 0; e < 8; ++e) {
            float x0 = s[e];
            u16 h0 = f2bf(x0);
            ph0[e] = (short)h0; pl0[e] = (short)f2bf(x0 - bf2f(h0));
            float x1 = s[8 + e];
            u16 h1 = f2bf(x1);
            ph1[e] = (short)h1; pl1[e] = (short)f2bf(x1 - bf2f(h1));
        }

        const u16* vbh = VH + cb * 2560;
        const u16* vbl = VL + cb * 2560;
        __builtin_amdgcn_s_setprio(1);
#pragma unroll
        for (int d = 0; d < 2; ++d) {
            f32x16 acc = d ? o1 : o0;
#pragma unroll
            for (int c = 0; c < 2; ++c) {
                const u16* ph_ = vbh + (d * 32 + l31) * 40 + c * 16 + g * 4;
                const u16* pl_ = vbl + (d * 32 + l31) * 40 + c * 16 + g * 4;
                bf16x4 h0 = *(const bf16x4*)(ph_);
                bf16x4 h1 = *(const bf16x4*)(ph_ + 8);
                bf16x4 l0 = *(const bf16x4*)(pl_);
                bf16x4 l1 = *(const bf16x4*)(pl_ + 8);
                bf16x8 vh8 = __builtin_shufflevector(h0, h1, 0, 1, 2, 3, 4, 5, 6, 7);
                bf16x8 vl8 = __builtin_shufflevector(l0, l1, 0, 1, 2, 3, 4, 5, 6, 7);
                bf16x8 pc = c ? ph1 : ph0;
                bf16x8 plc = c ? pl1 : pl0;
                acc = MFMA32(vh8, pc, acc);
                acc = MFMA32(vl8, pc, acc);
                acc = MFMA32(vh8, plc, acc);
            }
            if (d) o1 = acc; else o0 = acc;
        }
        __builtin_amdgcn_s_setprio(0);

        if (it < 31) WRITET(cb ^ 1);
        __syncthreads();
    }

    float inv = 1.0f / l_run;
    float* op = out + qtok * 64;
#pragma unroll
    for (int d = 0; d < 2; ++d) {
#pragma unroll
        for (int sg = 0; sg < 4; ++sg) {
            float4 o4;
            if (d == 0) o4 = make_float4(o0[4*sg+0]*inv, o0[4*sg+1]*inv, o0[4*sg+2]*inv, o0[4*sg+3]*inv);
            else        o4 = make_float4(o1[4*sg+0]*inv, o1[4*sg+1]*inv, o1[4*sg+2]*inv, o1[4*sg+3]*inv);
            *(float4*)(op + d * 32 + sg * 8 + g * 4) = o4;
        }
    }
#undef LOADT
#undef WRITET
}

extern "C" void kernel_launch(void* const* d_in, const int* in_sizes, int n_in,
                              void* d_out, int out_size, void* d_ws, size_t ws_size,
                              hipStream_t stream) {
    const float* vectors = (const float*)d_in[0];
    const float* scalars = (const float*)d_in[1];
    const float* Wq   = (const float*)d_in[2];
    const float* Wq_s = (const float*)d_in[3];
    const float* bq_s = (const float*)d_in[4];
    const float* Wk   = (const float*)d_in[5];
    const float* Wk_s = (const float*)d_in[6];
    const float* bk_s = (const float*)d_in[7];
    const float* Wv   = (const float*)d_in[8];
    float* o = (float*)d_out;

    u16* qh  = (u16*)d_ws;                 // 64*1024*192 each
    u16* ql  = qh + 12582912;
    u16* kh  = ql + 12582912;
    u16* kl  = kh + 12582912;
    u16* vth = kl + 12582912;              // 64*64*1024 each
    u16* vtl = vth + 4194304;

    prep_kernel<<<1024, 256, 0, stream>>>(vectors, scalars, Wq, Wq_s, bq_s,
                                          Wk, Wk_s, bk_s, Wv,
                                          qh, ql, kh, kl, vth, vtl);
    attn_kernel<<<512, 256, 0, stream>>>(qh, ql, kh, kl, vth, vtl, o);
}